// Round 1
// baseline (378.588 us; speedup 1.0000x reference)
//
#include <hip/hip_runtime.h>
#include <hip/hip_bf16.h>
#include <cstdint>

typedef __bf16 bf16x8 __attribute__((ext_vector_type(8)));
typedef float f32x4 __attribute__((ext_vector_type(4)));

#define M_DIM 8192
#define H_DIM 1024
#define K_DIM 2048
#define BM 128
#define BK 64

__device__ __forceinline__ void async_copy16(void* lds, const void* g) {
    __builtin_amdgcn_global_load_lds(
        (const __attribute__((address_space(1))) uint32_t*)g,
        (__attribute__((address_space(3))) uint32_t*)lds, 16, 0, 0);
}

__device__ __forceinline__ float fast_sigmoid(float x) {
    return 1.0f / (1.0f + __expf(-x));
}
__device__ __forceinline__ float fast_tanh(float x) {
    float t = __expf(-2.0f * x);
    return (1.0f - t) / (1.0f + t);
}

// ---- pack A = [x | h] cast to bf16, row-major [8192][2048] ----
__global__ void pack_a_kernel(const float* __restrict__ x,
                              const float* __restrict__ h,
                              __bf16* __restrict__ A) {
    int tid = blockIdx.x * blockDim.x + threadIdx.x;  // 8192*256 threads
    int row = tid >> 8;
    int col = (tid & 255) * 8;
    const float* src = (col < 1024) ? (x + (size_t)row * 1024 + col)
                                    : (h + (size_t)row * 1024 + (col - 1024));
    float4 v0 = ((const float4*)src)[0];
    float4 v1 = ((const float4*)src)[1];
    union { __bf16 b[8]; uint4 u; } p;
    p.b[0] = (__bf16)v0.x; p.b[1] = (__bf16)v0.y;
    p.b[2] = (__bf16)v0.z; p.b[3] = (__bf16)v0.w;
    p.b[4] = (__bf16)v1.x; p.b[5] = (__bf16)v1.y;
    p.b[6] = (__bf16)v1.z; p.b[7] = (__bf16)v1.w;
    *((uint4*)(A + (size_t)row * K_DIM + col)) = p.u;
}

// ---- pack Bt[n][k] = (k<1024 ? Wx[k][n] : Wh[k-1024][n]) as bf16 ----
__global__ void pack_bt_kernel(const float* __restrict__ Wx,
                               const float* __restrict__ Wh,
                               __bf16* __restrict__ Bt) {
    __shared__ float tile[32][33];
    int n0 = blockIdx.x * 32;   // 0..4095
    int k0 = blockIdx.y * 32;   // 0..2047
    const float* W = (k0 < 1024) ? (Wx + (size_t)k0 * 4096)
                                 : (Wh + (size_t)(k0 - 1024) * 4096);
    int tx = threadIdx.x;  // 0..31
    int ty = threadIdx.y;  // 0..7
    #pragma unroll
    for (int r = ty; r < 32; r += 8)
        tile[r][tx] = W[(size_t)r * 4096 + n0 + tx];
    __syncthreads();
    #pragma unroll
    for (int r = ty; r < 32; r += 8) {
        int n = n0 + r;
        int k = k0 + tx;
        Bt[(size_t)n * K_DIM + k] = (__bf16)tile[tx][r];
    }
}

// ---- fused GEMM + LSTM epilogue ----
// grid (64, 32): blockIdx.x -> 128 batch rows, blockIdx.y -> 32 output cols.
// Tile N=128 = 4 gates x 32 cols (Bt rows g*1024 + jbase + d).
// Wave (wm, wn): rows wm*64+s*16, n-tiles ct = 2t+wn -> gate t, col jbase+wn*16+lane%16.
// => all 4 gates for an output column live in one lane's acc[s][0..3]. Lane-local epilogue.
__global__ __launch_bounds__(256) void lstm_gemm(
    const __bf16* __restrict__ A, const __bf16* __restrict__ Bt,
    const float* __restrict__ bx, const float* __restrict__ cin,
    float* __restrict__ out) {
    __shared__ __bf16 lA[BM * BK];
    __shared__ __bf16 lB[BM * BK];

    const int tid = threadIdx.x;
    const int lane = tid & 63;
    const int wid = tid >> 6;
    const int wm = wid >> 1, wn = wid & 1;
    const int bm0 = blockIdx.x * BM;
    const int jbase = blockIdx.y * 32;

    const int l8 = lane >> 3, c8 = lane & 7;
    size_t aoff[4], boff[4];
    int ldso[4];
    #pragma unroll
    for (int q = 0; q < 4; ++q) {
        int r = wid * 32 + q * 8 + l8;              // LDS row 0..127
        aoff[q] = (size_t)(bm0 + r) * K_DIM + c8 * 8;
        int n = wid * H_DIM + jbase + q * 8 + l8;   // gate = wid
        boff[q] = (size_t)n * K_DIM + c8 * 8;
        ldso[q] = (wid * 32 + q * 8) * BK;
    }

    f32x4 acc[4][4];
    #pragma unroll
    for (int s = 0; s < 4; ++s)
        #pragma unroll
        for (int t = 0; t < 4; ++t)
            acc[s][t] = f32x4{0.f, 0.f, 0.f, 0.f};

    const int lm = lane & 15, lu = lane >> 4;

    for (int ks = 0; ks < K_DIM / BK; ++ks) {
        __syncthreads();
        const int ko = ks * BK;
        #pragma unroll
        for (int q = 0; q < 4; ++q) {
            async_copy16(lA + ldso[q], A + aoff[q] + ko);
            async_copy16(lB + ldso[q], Bt + boff[q] + ko);
        }
        __syncthreads();
        #pragma unroll
        for (int kk = 0; kk < 2; ++kk) {
            bf16x8 af[4], bfr[4];
            #pragma unroll
            for (int s = 0; s < 4; ++s)
                af[s] = *(const bf16x8*)(lA + (wm * 64 + s * 16 + lm) * BK + kk * 32 + lu * 8);
            #pragma unroll
            for (int t = 0; t < 4; ++t)
                bfr[t] = *(const bf16x8*)(lB + ((2 * t + wn) * 16 + lm) * BK + kk * 32 + lu * 8);
            #pragma unroll
            for (int s = 0; s < 4; ++s)
                #pragma unroll
                for (int t = 0; t < 4; ++t)
                    acc[s][t] = __builtin_amdgcn_mfma_f32_16x16x32_bf16(
                        af[s], bfr[t], acc[s][t], 0, 0, 0);
        }
    }

    // ---- LSTM epilogue (lane-local: acc[s][0..3] = i,f,g,o for col j) ----
    const int j = jbase + wn * 16 + lm;
    const float bi = bx[j];
    const float bff = bx[H_DIM + j];
    const float bg = bx[2 * H_DIM + j];
    const float bo = bx[3 * H_DIM + j];
    #pragma unroll
    for (int s = 0; s < 4; ++s) {
        #pragma unroll
        for (int r = 0; r < 4; ++r) {
            const int row = bm0 + wm * 64 + s * 16 + lu * 4 + r;
            const size_t off = (size_t)row * H_DIM + j;
            float iv = fast_sigmoid(acc[s][0][r] + bi);
            float fv = fast_sigmoid(acc[s][1][r] + bff);
            float gv = fast_tanh(acc[s][2][r] + bg);
            float ov = fast_sigmoid(acc[s][3][r] + bo);
            float cn = fv * cin[off] + iv * gv;
            out[off] = ov * fast_tanh(cn);
            out[(size_t)M_DIM * H_DIM + off] = cn;
        }
    }
}

extern "C" void kernel_launch(void* const* d_in, const int* in_sizes, int n_in,
                              void* d_out, int out_size, void* d_ws, size_t ws_size,
                              hipStream_t stream) {
    const float* x  = (const float*)d_in[0];
    const float* h  = (const float*)d_in[1];
    const float* c  = (const float*)d_in[2];
    const float* Wx = (const float*)d_in[3];
    const float* bx = (const float*)d_in[4];
    const float* Wh = (const float*)d_in[5];
    float* out = (float*)d_out;

    __bf16* A  = (__bf16*)d_ws;                                      // 32 MB
    __bf16* Bt = (__bf16*)((char*)d_ws + (size_t)M_DIM * K_DIM * 2); // 16 MB

    pack_a_kernel<<<M_DIM, 256, 0, stream>>>(x, h, A);
    pack_bt_kernel<<<dim3(4096 / 32, K_DIM / 32), dim3(32, 8), 0, stream>>>(Wx, Wh, Bt);
    lstm_gemm<<<dim3(M_DIM / BM, H_DIM / 32), 256, 0, stream>>>(A, Bt, bx, c, out);
}

// Round 2
// 337.620 us; speedup vs baseline: 1.1213x; 1.1213x over previous
//
#include <hip/hip_runtime.h>
#include <hip/hip_bf16.h>
#include <cstdint>

typedef __bf16 bf16x8 __attribute__((ext_vector_type(8)));
typedef float f32x4 __attribute__((ext_vector_type(4)));

#define M_DIM 8192
#define H_DIM 1024
#define K_DIM 2048
#define BM 128
#define BK 64

__device__ __forceinline__ void async_copy16(void* lds, const void* g) {
    __builtin_amdgcn_global_load_lds(
        (const __attribute__((address_space(1))) uint32_t*)g,
        (__attribute__((address_space(3))) uint32_t*)lds, 16, 0, 0);
}

__device__ __forceinline__ float fast_sigmoid(float x) {
    return 1.0f / (1.0f + __expf(-x));
}
__device__ __forceinline__ float fast_tanh(float x) {
    float t = __expf(-2.0f * x);
    return (1.0f - t) / (1.0f + t);
}

// ---- pack A = [x | h] cast to bf16, row-major [8192][2048], XOR-swizzled ----
// Logical 16B-chunk c of row r is stored at chunk position (c&~7)|((c&7)^(r&7)).
__global__ void pack_a_kernel(const float* __restrict__ x,
                              const float* __restrict__ h,
                              __bf16* __restrict__ A) {
    int tid = blockIdx.x * blockDim.x + threadIdx.x;
    int row = tid >> 8;
    int c = tid & 255;                 // logical chunk 0..255
    int col = c * 8;
    const float* src = (col < 1024) ? (x + (size_t)row * 1024 + col)
                                    : (h + (size_t)row * 1024 + (col - 1024));
    float4 v0 = ((const float4*)src)[0];
    float4 v1 = ((const float4*)src)[1];
    union { __bf16 b[8]; uint4 u; } p;
    p.b[0] = (__bf16)v0.x; p.b[1] = (__bf16)v0.y;
    p.b[2] = (__bf16)v0.z; p.b[3] = (__bf16)v0.w;
    p.b[4] = (__bf16)v1.x; p.b[5] = (__bf16)v1.y;
    p.b[6] = (__bf16)v1.z; p.b[7] = (__bf16)v1.w;
    int sw = (c & ~7) | ((c & 7) ^ (row & 7));     // swizzled chunk position
    *((uint4*)(A + (size_t)row * K_DIM + sw * 8)) = p.u;
}

// ---- pack Bt[n][k] = (k<1024 ? Wx[k][n] : Wh[k-1024][n]) as bf16, swizzled ----
__global__ void pack_bt_kernel(const float* __restrict__ Wx,
                               const float* __restrict__ Wh,
                               __bf16* __restrict__ Bt) {
    __shared__ float tile[32][33];
    int n0 = blockIdx.x * 32;
    int k0 = blockIdx.y * 32;
    const float* W = (k0 < 1024) ? (Wx + (size_t)k0 * 4096)
                                 : (Wh + (size_t)(k0 - 1024) * 4096);
    int tx = threadIdx.x;  // 0..31
    int ty = threadIdx.y;  // 0..7
    #pragma unroll
    for (int r = ty; r < 32; r += 8)
        tile[r][tx] = W[(size_t)r * 4096 + n0 + tx];
    __syncthreads();
    #pragma unroll
    for (int r = ty; r < 32; r += 8) {
        int n = n0 + r;
        int k = k0 + tx;               // logical k
        int c = k >> 3;
        int sw = (c & ~7) | ((c & 7) ^ (n & 7));
        Bt[(size_t)n * K_DIM + sw * 8 + (k & 7)] = (__bf16)tile[tx][r];
    }
}

// ---- fused GEMM + LSTM epilogue ----
// grid (64, 32): blockIdx.x -> 128 batch rows, blockIdx.y -> 32 output cols.
// Tile N=128 = 4 gates x 32 cols. All 4 gates for one output column land in
// one lane's acc[s][0..3] -> lane-local LSTM epilogue, gates never hit HBM.
// LDS is XOR-swizzled (see pack kernels) to kill ds_read_b128 bank conflicts:
// lanes lm=0..7 read chunk (kk*4+lu)^(lm&7) -> all 32 banks; lm vs lm+8 is
// 2-way (free per m136).
__global__ __launch_bounds__(256) void lstm_gemm(
    const __bf16* __restrict__ A, const __bf16* __restrict__ Bt,
    const float* __restrict__ bx, const float* __restrict__ cin,
    float* __restrict__ out) {
    __shared__ __bf16 lA[BM * BK];
    __shared__ __bf16 lB[BM * BK];

    const int tid = threadIdx.x;
    const int lane = tid & 63;
    const int wid = tid >> 6;
    const int wm = wid >> 1, wn = wid & 1;
    const int bm0 = blockIdx.x * BM;
    const int jbase = blockIdx.y * 32;

    const int l8 = lane >> 3, c8 = lane & 7;
    size_t aoff[4], boff[4];
    int ldso[4];
    #pragma unroll
    for (int q = 0; q < 4; ++q) {
        int r = wid * 32 + q * 8 + l8;              // LDS row 0..127
        aoff[q] = (size_t)(bm0 + r) * K_DIM + c8 * 8;
        int n = wid * H_DIM + jbase + q * 8 + l8;   // gate = wid
        boff[q] = (size_t)n * K_DIM + c8 * 8;
        ldso[q] = (wid * 32 + q * 8) * BK;
    }

    f32x4 acc[4][4];
    #pragma unroll
    for (int s = 0; s < 4; ++s)
        #pragma unroll
        for (int t = 0; t < 4; ++t)
            acc[s][t] = f32x4{0.f, 0.f, 0.f, 0.f};

    const int lm = lane & 15, lu = lane >> 4;
    const int sw7 = lm & 7;                          // row&7 for swizzle

    for (int ks = 0; ks < K_DIM / BK; ++ks) {
        __syncthreads();
        const int ko = ks * BK;
        #pragma unroll
        for (int q = 0; q < 4; ++q) {
            async_copy16(lA + ldso[q], A + aoff[q] + ko);
            async_copy16(lB + ldso[q], Bt + boff[q] + ko);
        }
        __syncthreads();
        #pragma unroll
        for (int kk = 0; kk < 2; ++kk) {
            const int jsw = ((kk * 4 + lu) ^ sw7) * 16;   // swizzled byte offset in row
            bf16x8 af[4], bfr[4];
            #pragma unroll
            for (int s = 0; s < 4; ++s)
                af[s] = *(const bf16x8*)((const char*)lA + (wm * 64 + s * 16 + lm) * (BK * 2) + jsw);
            #pragma unroll
            for (int t = 0; t < 4; ++t)
                bfr[t] = *(const bf16x8*)((const char*)lB + ((2 * t + wn) * 16 + lm) * (BK * 2) + jsw);
            #pragma unroll
            for (int s = 0; s < 4; ++s)
                #pragma unroll
                for (int t = 0; t < 4; ++t)
                    acc[s][t] = __builtin_amdgcn_mfma_f32_16x16x32_bf16(
                        af[s], bfr[t], acc[s][t], 0, 0, 0);
        }
    }

    // ---- LSTM epilogue (lane-local: acc[s][0..3] = i,f,g,o for col j) ----
    const int j = jbase + wn * 16 + lm;
    const float bi = bx[j];
    const float bff = bx[H_DIM + j];
    const float bg = bx[2 * H_DIM + j];
    const float bo = bx[3 * H_DIM + j];
    #pragma unroll
    for (int s = 0; s < 4; ++s) {
        #pragma unroll
        for (int r = 0; r < 4; ++r) {
            const int row = bm0 + wm * 64 + s * 16 + lu * 4 + r;
            const size_t off = (size_t)row * H_DIM + j;
            float iv = fast_sigmoid(acc[s][0][r] + bi);
            float fv = fast_sigmoid(acc[s][1][r] + bff);
            float gv = fast_tanh(acc[s][2][r] + bg);
            float ov = fast_sigmoid(acc[s][3][r] + bo);
            float cn = fv * cin[off] + iv * gv;
            out[off] = ov * fast_tanh(cn);
            out[(size_t)M_DIM * H_DIM + off] = cn;
        }
    }
}

extern "C" void kernel_launch(void* const* d_in, const int* in_sizes, int n_in,
                              void* d_out, int out_size, void* d_ws, size_t ws_size,
                              hipStream_t stream) {
    const float* x  = (const float*)d_in[0];
    const float* h  = (const float*)d_in[1];
    const float* c  = (const float*)d_in[2];
    const float* Wx = (const float*)d_in[3];
    const float* bx = (const float*)d_in[4];
    const float* Wh = (const float*)d_in[5];
    float* out = (float*)d_out;

    __bf16* A  = (__bf16*)d_ws;                                      // 32 MB
    __bf16* Bt = (__bf16*)((char*)d_ws + (size_t)M_DIM * K_DIM * 2); // 16 MB

    pack_a_kernel<<<M_DIM, 256, 0, stream>>>(x, h, A);
    pack_bt_kernel<<<dim3(4096 / 32, K_DIM / 32), dim3(32, 8), 0, stream>>>(Wx, Wh, Bt);
    lstm_gemm<<<dim3(M_DIM / BM, H_DIM / 32), 256, 0, stream>>>(A, Bt, bx, c, out);
}

// Round 3
// 330.121 us; speedup vs baseline: 1.1468x; 1.0227x over previous
//
#include <hip/hip_runtime.h>
#include <hip/hip_bf16.h>
#include <cstdint>

typedef __bf16 bf16x8 __attribute__((ext_vector_type(8)));
typedef float f32x4 __attribute__((ext_vector_type(4)));

#define M_DIM 8192
#define H_DIM 1024
#define K_DIM 2048
#define BM 128
#define BK 64
#define BMBK (BM * BK)

#define NBT_BLOCKS 2048
#define NA_BLOCKS 2048

__device__ __forceinline__ void async_copy16(void* lds, const void* g) {
    __builtin_amdgcn_global_load_lds(
        (const __attribute__((address_space(1))) uint32_t*)g,
        (__attribute__((address_space(3))) uint32_t*)lds, 16, 0, 0);
}

__device__ __forceinline__ float fast_sigmoid(float x) {
    return 1.0f / (1.0f + __expf(-x));
}
__device__ __forceinline__ float fast_tanh(float x) {
    float t = __expf(-2.0f * x);
    return (1.0f - t) / (1.0f + t);
}

// ---- fused pack: A = bf16([x|h]) swizzled; Bt = bf16(W^T) swizzled ----
// Swizzle: logical 16B-chunk c of row r stored at chunk pos (c&~7)|((c&7)^(r&7)).
// Bt blocks: 64n x 64k tile, float4 loads -> LDS (stride 65: 2-way max = free)
// -> uint4 stores; 8 chunks/row = fully dense 128B windows.
__global__ __launch_bounds__(256) void pack_all(
    const float* __restrict__ x, const float* __restrict__ h,
    const float* __restrict__ Wx, const float* __restrict__ Wh,
    __bf16* __restrict__ A, __bf16* __restrict__ Bt) {
    __shared__ float tile[64 * 65];
    const int b = blockIdx.x;
    const int t = threadIdx.x;
    if (b < NBT_BLOCKS) {
        const int bn = b & 63;          // 64 n-tiles
        const int bk = b >> 6;          // 32 k-tiles
        const int n0 = bn * 64, k0 = bk * 64;
        const float* W = (k0 < 1024) ? Wx + (size_t)k0 * 4096
                                     : Wh + (size_t)(k0 - 1024) * 4096;
        #pragma unroll
        for (int i = 0; i < 4; ++i) {
            int p = t + i * 256;        // 0..1023 float4 slots
            int kr = p >> 4, c4 = p & 15;
            float4 v = *(const float4*)(W + (size_t)kr * 4096 + n0 + c4 * 4);
            float* dst = tile + kr * 65 + c4 * 4;
            dst[0] = v.x; dst[1] = v.y; dst[2] = v.z; dst[3] = v.w;
        }
        __syncthreads();
        #pragma unroll
        for (int i = 0; i < 2; ++i) {
            int p = t + i * 256;        // 0..511 (n, chunk) pairs
            int n = p >> 3, ch = p & 7;
            int ng = n0 + n;
            union { __bf16 bb[8]; uint4 u; } pk;
            #pragma unroll
            for (int j = 0; j < 8; ++j)
                pk.bb[j] = (__bf16)tile[(ch * 8 + j) * 65 + n];
            int c = (k0 >> 3) + ch;
            int sw = (c & ~7) | ((c & 7) ^ (ng & 7));
            *(uint4*)(Bt + (size_t)ng * K_DIM + sw * 8) = pk.u;
        }
    } else {
        const int ab = b - NBT_BLOCKS;  // 4 batch rows per block
        #pragma unroll
        for (int i = 0; i < 4; ++i) {
            int p = t + i * 256;        // 0..1023
            int row = ab * 4 + (p >> 8);
            int c = p & 255;
            int col = c * 8;
            const float* src = (col < 1024) ? x + (size_t)row * 1024 + col
                                            : h + (size_t)row * 1024 + (col - 1024);
            float4 v0 = ((const float4*)src)[0];
            float4 v1 = ((const float4*)src)[1];
            union { __bf16 bb[8]; uint4 u; } pk;
            pk.bb[0] = (__bf16)v0.x; pk.bb[1] = (__bf16)v0.y;
            pk.bb[2] = (__bf16)v0.z; pk.bb[3] = (__bf16)v0.w;
            pk.bb[4] = (__bf16)v1.x; pk.bb[5] = (__bf16)v1.y;
            pk.bb[6] = (__bf16)v1.z; pk.bb[7] = (__bf16)v1.w;
            int sw = (c & ~7) | ((c & 7) ^ (row & 7));
            *(uint4*)(A + (size_t)row * K_DIM + sw * 8) = pk.u;
        }
    }
}

// ---- fused GEMM + LSTM epilogue, double-buffered LDS ----
// One __syncthreads per K-iter: barrier's forced vmcnt(0) drains tile-k loads
// that were issued BEFORE tile k-1's compute -> drain is cheap (loads had a
// full compute phase in flight). Prefetch for k+1 issues right after barrier
// into the other buffer (safe: barrier also guarantees prev compute done).
__global__ __launch_bounds__(256) void lstm_gemm(
    const __bf16* __restrict__ A, const __bf16* __restrict__ Bt,
    const float* __restrict__ bx, const float* __restrict__ cin,
    float* __restrict__ out) {
    __shared__ __bf16 lds[2][2 * BMBK];   // [buf][A(16KB) then B(16KB)] = 64KB

    const int tid = threadIdx.x;
    const int lane = tid & 63;
    const int wid = tid >> 6;
    const int wm = wid >> 1, wn = wid & 1;
    const int bm0 = blockIdx.x * BM;
    const int jbase = blockIdx.y * 32;

    const int l8 = lane >> 3, c8 = lane & 7;
    const __bf16* pA[4];
    const __bf16* pB[4];
    int ldso[4];
    #pragma unroll
    for (int q = 0; q < 4; ++q) {
        int r = wid * 32 + q * 8 + l8;              // LDS row 0..127
        pA[q] = A + (size_t)(bm0 + r) * K_DIM + c8 * 8;
        int n = wid * H_DIM + jbase + q * 8 + l8;   // gate = wid
        pB[q] = Bt + (size_t)n * K_DIM + c8 * 8;
        ldso[q] = (wid * 32 + q * 8) * BK;
    }

    f32x4 acc[4][4];
    #pragma unroll
    for (int s = 0; s < 4; ++s)
        #pragma unroll
        for (int t = 0; t < 4; ++t)
            acc[s][t] = f32x4{0.f, 0.f, 0.f, 0.f};

    const int lm = lane & 15, lu = lane >> 4;
    const int sw7 = lm & 7;

    // preload tile 0 into buf 0
    #pragma unroll
    for (int q = 0; q < 4; ++q) {
        async_copy16(&lds[0][ldso[q]], pA[q]);
        async_copy16(&lds[0][BMBK + ldso[q]], pB[q]);
    }

    const int NK = K_DIM / BK;  // 32
    for (int ks = 0; ks < NK; ++ks) {
        const int cur = ks & 1;
        __syncthreads();   // vmcnt(0) drain: tile ks loads done; prev compute done
        if (ks + 1 < NK) {
            const int ko = (ks + 1) * BK;
            #pragma unroll
            for (int q = 0; q < 4; ++q) {
                async_copy16(&lds[cur ^ 1][ldso[q]], pA[q] + ko);
                async_copy16(&lds[cur ^ 1][BMBK + ldso[q]], pB[q] + ko);
            }
        }
        const __bf16* lA = lds[cur];
        const __bf16* lB = lds[cur] + BMBK;
        #pragma unroll
        for (int kk = 0; kk < 2; ++kk) {
            const int jsw = ((kk * 4 + lu) ^ sw7) * 16;   // swizzled byte offset
            bf16x8 af[4], bfr[4];
            #pragma unroll
            for (int s = 0; s < 4; ++s)
                af[s] = *(const bf16x8*)((const char*)lA + (wm * 64 + s * 16 + lm) * (BK * 2) + jsw);
            #pragma unroll
            for (int t = 0; t < 4; ++t)
                bfr[t] = *(const bf16x8*)((const char*)lB + ((2 * t + wn) * 16 + lm) * (BK * 2) + jsw);
            #pragma unroll
            for (int s = 0; s < 4; ++s)
                #pragma unroll
                for (int t = 0; t < 4; ++t)
                    acc[s][t] = __builtin_amdgcn_mfma_f32_16x16x32_bf16(
                        af[s], bfr[t], acc[s][t], 0, 0, 0);
        }
    }

    // ---- LSTM epilogue (lane-local: acc[s][0..3] = i,f,g,o for col j) ----
    const int j = jbase + wn * 16 + lm;
    const float bi = bx[j];
    const float bff = bx[H_DIM + j];
    const float bg = bx[2 * H_DIM + j];
    const float bo = bx[3 * H_DIM + j];
    #pragma unroll
    for (int s = 0; s < 4; ++s) {
        #pragma unroll
        for (int r = 0; r < 4; ++r) {
            const int row = bm0 + wm * 64 + s * 16 + lu * 4 + r;
            const size_t off = (size_t)row * H_DIM + j;
            float iv = fast_sigmoid(acc[s][0][r] + bi);
            float fv = fast_sigmoid(acc[s][1][r] + bff);
            float gv = fast_tanh(acc[s][2][r] + bg);
            float ov = fast_sigmoid(acc[s][3][r] + bo);
            float cn = fv * cin[off] + iv * gv;
            out[off] = ov * fast_tanh(cn);
            out[(size_t)M_DIM * H_DIM + off] = cn;
        }
    }
}

extern "C" void kernel_launch(void* const* d_in, const int* in_sizes, int n_in,
                              void* d_out, int out_size, void* d_ws, size_t ws_size,
                              hipStream_t stream) {
    const float* x  = (const float*)d_in[0];
    const float* h  = (const float*)d_in[1];
    const float* c  = (const float*)d_in[2];
    const float* Wx = (const float*)d_in[3];
    const float* bx = (const float*)d_in[4];
    const float* Wh = (const float*)d_in[5];
    float* out = (float*)d_out;

    __bf16* A  = (__bf16*)d_ws;                                      // 32 MB
    __bf16* Bt = (__bf16*)((char*)d_ws + (size_t)M_DIM * K_DIM * 2); // 16 MB

    pack_all<<<NBT_BLOCKS + NA_BLOCKS, 256, 0, stream>>>(x, h, Wx, Wh, A, Bt);
    lstm_gemm<<<dim3(M_DIM / BM, H_DIM / 32), 256, 0, stream>>>(A, Bt, bx, c, out);
}

// Round 4
// 293.046 us; speedup vs baseline: 1.2919x; 1.1265x over previous
//
#include <hip/hip_runtime.h>
#include <hip/hip_bf16.h>
#include <cstdint>

typedef __bf16 bf16x8 __attribute__((ext_vector_type(8)));
typedef float f32x4 __attribute__((ext_vector_type(4)));

#define M_DIM 8192
#define H_DIM 1024
#define K_DIM 2048
#define BM 128
#define BK 64
#define BMBK (BM * BK)

__device__ __forceinline__ void async_copy16(void* lds, const void* g) {
    __builtin_amdgcn_global_load_lds(
        (const __attribute__((address_space(1))) uint32_t*)g,
        (__attribute__((address_space(3))) uint32_t*)lds, 16, 0, 0);
}

__device__ __forceinline__ float fast_sigmoid(float x) {
    return __builtin_amdgcn_rcpf(1.0f + __expf(-x));
}
__device__ __forceinline__ float fast_tanh(float x) {
    float t = __expf(-2.0f * x);
    return (1.0f - t) * __builtin_amdgcn_rcpf(1.0f + t);
}

// ---- pack A = bf16([x|h]), row-major [8192][2048], XOR-swizzled ----
// Logical 16B-chunk c of row r stored at chunk pos (c&~7)|((c&7)^(r&7)).
__global__ __launch_bounds__(256) void pack_a(
    const float* __restrict__ x, const float* __restrict__ h,
    __bf16* __restrict__ A) {
    const int ab = blockIdx.x;          // 4 batch rows per block
    const int t = threadIdx.x;
    #pragma unroll
    for (int i = 0; i < 4; ++i) {
        int p = t + i * 256;            // 0..1023
        int row = ab * 4 + (p >> 8);
        int c = p & 255;
        int col = c * 8;
        const float* src = (col < 1024) ? x + (size_t)row * 1024 + col
                                        : h + (size_t)row * 1024 + (col - 1024);
        float4 v0 = ((const float4*)src)[0];
        float4 v1 = ((const float4*)src)[1];
        union { __bf16 bb[8]; uint4 u; } pk;
        pk.bb[0] = (__bf16)v0.x; pk.bb[1] = (__bf16)v0.y;
        pk.bb[2] = (__bf16)v0.z; pk.bb[3] = (__bf16)v0.w;
        pk.bb[4] = (__bf16)v1.x; pk.bb[5] = (__bf16)v1.y;
        pk.bb[6] = (__bf16)v1.z; pk.bb[7] = (__bf16)v1.w;
        int sw = (c & ~7) | ((c & 7) ^ (row & 7));
        *(uint4*)(A + (size_t)row * K_DIM + sw * 8) = pk.u;
    }
}

// ---- pack Bt[n][k] = bf16(W^T), XOR-swizzled; 64n x 64k LDS-transpose tiles ----
__global__ __launch_bounds__(256) void pack_bt(
    const float* __restrict__ Wx, const float* __restrict__ Wh,
    __bf16* __restrict__ Bt) {
    __shared__ float tile[64 * 65];
    const int b = blockIdx.x;
    const int t = threadIdx.x;
    const int bn = b & 63;
    const int bk = b >> 6;
    const int n0 = bn * 64, k0 = bk * 64;
    const float* W = (k0 < 1024) ? Wx + (size_t)k0 * 4096
                                 : Wh + (size_t)(k0 - 1024) * 4096;
    #pragma unroll
    for (int i = 0; i < 4; ++i) {
        int p = t + i * 256;
        int kr = p >> 4, c4 = p & 15;
        float4 v = *(const float4*)(W + (size_t)kr * 4096 + n0 + c4 * 4);
        float* dst = tile + kr * 65 + c4 * 4;
        dst[0] = v.x; dst[1] = v.y; dst[2] = v.z; dst[3] = v.w;
    }
    __syncthreads();
    #pragma unroll
    for (int i = 0; i < 2; ++i) {
        int p = t + i * 256;
        int n = p >> 3, ch = p & 7;
        int ng = n0 + n;
        union { __bf16 bb[8]; uint4 u; } pk;
        #pragma unroll
        for (int j = 0; j < 8; ++j)
            pk.bb[j] = (__bf16)tile[(ch * 8 + j) * 65 + n];
        int c = (k0 >> 3) + ch;
        int sw = (c & ~7) | ((c & 7) ^ (ng & 7));
        *(uint4*)(Bt + (size_t)ng * K_DIM + sw * 8) = pk.u;
    }
}

// ---- fused GEMM + LSTM epilogue, double-buffered LDS ----
// 128x128 tile (N = 4 gates x 32 cols); all 4 gates of an output column land
// in one lane's acc[s][0..3] -> lane-local epilogue. cin prefetched into regs
// before the K-loop. LDS 64KB caps 2 blocks/CU, so launch_bounds(256,2)
// frees the VGPR budget for address/frag caching.
__global__ __launch_bounds__(256, 2) void lstm_gemm(
    const __bf16* __restrict__ A, const __bf16* __restrict__ Bt,
    const float* __restrict__ bx, const float* __restrict__ cin,
    float* __restrict__ out) {
    __shared__ __bf16 lds[2][2 * BMBK];   // [buf][A(16KB) then B(16KB)] = 64KB

    const int tid = threadIdx.x;
    const int lane = tid & 63;
    const int wid = tid >> 6;
    const int wm = wid >> 1, wn = wid & 1;
    const int bm0 = blockIdx.x * BM;
    const int jbase = blockIdx.y * 32;

    const int l8 = lane >> 3, c8 = lane & 7;
    const __bf16* pA[4];
    const __bf16* pB[4];
    int ldso[4];
    #pragma unroll
    for (int q = 0; q < 4; ++q) {
        int r = wid * 32 + q * 8 + l8;              // LDS row 0..127
        pA[q] = A + (size_t)(bm0 + r) * K_DIM + c8 * 8;
        int n = wid * H_DIM + jbase + q * 8 + l8;   // gate = wid
        pB[q] = Bt + (size_t)n * K_DIM + c8 * 8;
        ldso[q] = (wid * 32 + q * 8) * BK;
    }

    const int lm = lane & 15, lu = lane >> 4;
    const int sw7 = lm & 7;
    const int jsw0 = (lu ^ sw7) * 16;           // kk=0 swizzled byte offset
    const int jsw1 = ((4 + lu) ^ sw7) * 16;     // kk=1

    // prefetch cin for the epilogue (consumed only after the K-loop)
    const int j = jbase + wn * 16 + lm;
    f32x4 cpre[4];
    #pragma unroll
    for (int s = 0; s < 4; ++s)
        #pragma unroll
        for (int r = 0; r < 4; ++r) {
            const int row = bm0 + wm * 64 + s * 16 + lu * 4 + r;
            cpre[s][r] = cin[(size_t)row * H_DIM + j];
        }

    f32x4 acc[4][4];
    #pragma unroll
    for (int s = 0; s < 4; ++s)
        #pragma unroll
        for (int t = 0; t < 4; ++t)
            acc[s][t] = f32x4{0.f, 0.f, 0.f, 0.f};

    // preload tile 0 into buf 0
    #pragma unroll
    for (int q = 0; q < 4; ++q) {
        async_copy16(&lds[0][ldso[q]], pA[q]);
        async_copy16(&lds[0][BMBK + ldso[q]], pB[q]);
    }

    const int NK = K_DIM / BK;  // 32
    for (int ks = 0; ks < NK; ++ks) {
        const int cur = ks & 1;
        __syncthreads();   // tile ks loads drained; prev compute done
        if (ks + 1 < NK) {
            const int ko = (ks + 1) * BK;
            #pragma unroll
            for (int q = 0; q < 4; ++q) {
                async_copy16(&lds[cur ^ 1][ldso[q]], pA[q] + ko);
                async_copy16(&lds[cur ^ 1][BMBK + ldso[q]], pB[q] + ko);
            }
        }
        const __bf16* lA = lds[cur];
        const __bf16* lB = lds[cur] + BMBK;
        #pragma unroll
        for (int kk = 0; kk < 2; ++kk) {
            const int jsw = kk ? jsw1 : jsw0;
            bf16x8 af[4], bfr[4];
            #pragma unroll
            for (int s = 0; s < 4; ++s)
                af[s] = *(const bf16x8*)((const char*)lA + (wm * 64 + s * 16 + lm) * (BK * 2) + jsw);
            #pragma unroll
            for (int t = 0; t < 4; ++t)
                bfr[t] = *(const bf16x8*)((const char*)lB + ((2 * t + wn) * 16 + lm) * (BK * 2) + jsw);
            #pragma unroll
            for (int s = 0; s < 4; ++s)
                #pragma unroll
                for (int t = 0; t < 4; ++t)
                    acc[s][t] = __builtin_amdgcn_mfma_f32_16x16x32_bf16(
                        af[s], bfr[t], acc[s][t], 0, 0, 0);
        }
    }

    // ---- LSTM epilogue (lane-local: acc[s][0..3] = i,f,g,o for col j) ----
    const float bi = bx[j];
    const float bff = bx[H_DIM + j];
    const float bg = bx[2 * H_DIM + j];
    const float bo = bx[3 * H_DIM + j];
    #pragma unroll
    for (int s = 0; s < 4; ++s) {
        #pragma unroll
        for (int r = 0; r < 4; ++r) {
            const int row = bm0 + wm * 64 + s * 16 + lu * 4 + r;
            const size_t off = (size_t)row * H_DIM + j;
            float iv = fast_sigmoid(acc[s][0][r] + bi);
            float fv = fast_sigmoid(acc[s][1][r] + bff);
            float gv = fast_tanh(acc[s][2][r] + bg);
            float ov = fast_sigmoid(acc[s][3][r] + bo);
            float cn = fv * cpre[s][r] + iv * gv;
            out[off] = ov * fast_tanh(cn);
            out[(size_t)M_DIM * H_DIM + off] = cn;
        }
    }
}

extern "C" void kernel_launch(void* const* d_in, const int* in_sizes, int n_in,
                              void* d_out, int out_size, void* d_ws, size_t ws_size,
                              hipStream_t stream) {
    const float* x  = (const float*)d_in[0];
    const float* h  = (const float*)d_in[1];
    const float* c  = (const float*)d_in[2];
    const float* Wx = (const float*)d_in[3];
    const float* bx = (const float*)d_in[4];
    const float* Wh = (const float*)d_in[5];
    float* out = (float*)d_out;

    __bf16* A  = (__bf16*)d_ws;                                      // 32 MB
    __bf16* Bt = (__bf16*)((char*)d_ws + (size_t)M_DIM * K_DIM * 2); // 16 MB

    pack_a<<<M_DIM / 4, 256, 0, stream>>>(x, h, A);
    pack_bt<<<2048, 256, 0, stream>>>(Wx, Wh, Bt);
    lstm_gemm<<<dim3(M_DIM / BM, H_DIM / 32), 256, 0, stream>>>(A, Bt, bx, c, out);
}